// Round 5
// baseline (817.455 us; speedup 1.0000x reference)
//
#include <hip/hip_runtime.h>
#include <math.h>

static constexpr int BATCH = 4096;
static constexpr int NVIS  = 1024;
static constexpr int NHID  = 4096;
static constexpr int NCOND = 512;

typedef __attribute__((ext_vector_type(8))) short bf16x8;
typedef __attribute__((ext_vector_type(4))) float f32x4;

static constexpr unsigned HCAP = 131072;
static constexpr unsigned RCAP = 256;
static constexpr size_t MB = 1u << 20;

// ---------------- ws layout (~101.6 MiB, proven available in round 3) -------
static constexpr size_t F_WT0   = 0;                 // W^T planes [4096][1024]
static constexpr size_t F_WT1   = F_WT0  + 8*MB;
static constexpr size_t F_BMT0  = F_WT1  + 8*MB;     // B^T planes [4096][512]
static constexpr size_t F_BMT1  = F_BMT0 + 4*MB;
static constexpr size_t F_AT0   = F_BMT1 + 4*MB;     // A^T planes [1024][512]
static constexpr size_t F_AT1   = F_AT0  + 1*MB;
static constexpr size_t F_V0    = F_AT1  + 1*MB;     // vd planes [4096][1024]
static constexpr size_t F_V1    = F_V0   + 8*MB;
static constexpr size_t F_U0    = F_V1   + 8*MB;     // cd planes [4096][512]
static constexpr size_t F_U1    = F_U0   + 4*MB;
static constexpr size_t F_WR0   = F_U1   + 4*MB;     // W row-major planes [1024][4096]
static constexpr size_t F_WR1   = F_WR0  + 8*MB;
static constexpr size_t F_H     = F_WR1  + 8*MB;     // h bf16 [4096][4096]
static constexpr size_t F_BB    = F_H    + 32*MB;    // blockbest [4096][16] float4
static constexpr size_t F_HFLAG = F_BB   + 1*MB;
static constexpr size_t F_RFLAG = F_HFLAG + 512*1024;
static constexpr size_t F_RBEST = F_RFLAG + 16384;
static constexpr size_t F_CNT   = F_RBEST + 16384;
static constexpr size_t F_PREB  = F_CNT  + 256;
static constexpr size_t WS_FULL = F_PREB + 2*MB;

// ---------------- helpers ----------------
__device__ __forceinline__ void gload16(const void* g, void* l) {
    __builtin_amdgcn_global_load_lds(
        (const __attribute__((address_space(1))) void*)g,
        (__attribute__((address_space(3))) void*)l, 16, 0, 0);
}

__device__ __forceinline__ void split1(float x, unsigned short& hi, unsigned short& lo) {
    unsigned u = __float_as_uint(x);
    unsigned r = u + 0x7FFFu + ((u >> 16) & 1u);      // RN-even f32->bf16
    hi = (unsigned short)(r >> 16);
    float rem = x - __uint_as_float(r & 0xFFFF0000u); // exact (Sterbenz)
    unsigned u2 = __float_as_uint(rem);
    unsigned r2 = u2 + 0x7FFFu + ((u2 >> 16) & 1u);
    lo = (unsigned short)(r2 >> 16);
}

// top2 merge with first-index tiebreak; invariant s<=b on both inputs
__device__ __forceinline__ void merge3(float& b, unsigned& ix, float& s,
                                       float b2, unsigned i2, float s2) {
    if (b2 > b || (b2 == b && i2 < ix)) { s = fmaxf(b, s2); b = b2; ix = i2; }
    else                                { s = fmaxf(s, b2); }
}

// ---------------- prep kernels ----------------
__global__ void kz_zero(unsigned* c) { if (threadIdx.x < 64) c[threadIdx.x] = 0; }

// src [R][C] f32 -> d0/d1 [C][R] bf16 hi/lo planes
__global__ __launch_bounds__(256) void transpose_split(
    const float* __restrict__ src, int R, int C,
    unsigned short* __restrict__ d0, unsigned short* __restrict__ d1) {
    __shared__ float tile[32][33];
    const int c0 = blockIdx.x * 32, r0 = blockIdx.y * 32;
    const int tx = threadIdx.x & 31, ty = threadIdx.x >> 5;
#pragma unroll
    for (int e = 0; e < 4; ++e)
        tile[ty + e * 8][tx] = src[(size_t)(r0 + ty + e * 8) * C + c0 + tx];
    __syncthreads();
#pragma unroll
    for (int e = 0; e < 4; ++e) {
        int c = c0 + ty + e * 8;
        unsigned short hi, lo;
        split1(tile[tx][ty + e * 8], hi, lo);
        d0[(size_t)c * R + r0 + tx] = hi;
        d1[(size_t)c * R + r0 + tx] = lo;
    }
}

// elementwise split: src f32[n4*4] -> p0/p1 bf16 planes (same layout)
__global__ __launch_bounds__(256) void split_planes(
    const float* __restrict__ src, int n4,
    unsigned short* __restrict__ p0, unsigned short* __restrict__ p1) {
    for (int i = blockIdx.x * 256 + threadIdx.x; i < n4; i += gridDim.x * 256) {
        float4 v = ((const float4*)src)[i];
        unsigned short h0,h1,h2,h3,l0,l1,l2,l3;
        split1(v.x,h0,l0); split1(v.y,h1,l1); split1(v.z,h2,l2); split1(v.w,h3,l3);
        ((ushort4*)p0)[i] = make_ushort4(h0,h1,h2,h3);
        ((ushort4*)p1)[i] = make_ushort4(l0,l1,l2,l3);
    }
}

// ===========================================================================
// k1_p: z = v@W + u@B + c ; h(bf16) = noise < sigmoid(z); flag boundary bits.
// 128x128 tile, 256 thr, double-buffered LDS (64 KB). 2-phase prefetch:
// issue next tile's global_load_lds BEFORE current tile's compute; plain
// __syncthreads() (drains vmcnt+lgkm, compiler-safe) ends each step.
// grid (NHID/128, BATCH/128) = (32,32)
// ===========================================================================
__global__ __launch_bounds__(256, 2) void k1_p(
    const float* __restrict__ noise,
    const unsigned short* __restrict__ V0, const unsigned short* __restrict__ V1,
    const unsigned short* __restrict__ U0, const unsigned short* __restrict__ U1,
    const unsigned short* __restrict__ WT0, const unsigned short* __restrict__ WT1,
    const unsigned short* __restrict__ BmT0, const unsigned short* __restrict__ BmT1,
    const float* __restrict__ cvec, unsigned short* __restrict__ hout,
    unsigned* __restrict__ hcnt, unsigned* __restrict__ hflag)
{
    __shared__ __align__(16) unsigned short As0[2][128][32], As1[2][128][32],
                                            Bs0[2][128][32], Bs1[2][128][32];
    const int t = threadIdx.x, lane = t & 63, wid = t >> 6;
    const int g = lane >> 4, cc = lane & 15;
    const int wrow = wid >> 1, wcol = wid & 1;
    // XCD-aware bijective swizzle (nwg = 1024, divisible by 8)
    const int nwg = gridDim.x * gridDim.y;
    const int bid = blockIdx.y * gridDim.x + blockIdx.x;
    const int q = nwg >> 3;
    const int swz = (bid & 7) * q + (bid >> 3);
    const int b0 = (swz / gridDim.x) * 128;
    const int j0 = (swz % gridDim.x) * 128;

    auto stage = [&](int ks, int bi) {
        const unsigned short *A0_, *A1_, *B0_, *B1_; int K_, k0_;
        if (ks < 32) { A0_ = V0; A1_ = V1; B0_ = WT0; B1_ = WT1; K_ = 1024; k0_ = ks * 32; }
        else         { A0_ = U0; A1_ = U1; B0_ = BmT0; B1_ = BmT1; K_ = 512; k0_ = (ks - 32) * 32; }
#pragma unroll
        for (int e = 0; e < 2; ++e) {
            int idx = t + e * 256, r = idx >> 2, s = idx & 3;
            size_t ga = (size_t)(b0 + r) * K_ + k0_ + s * 8;
            size_t gb = (size_t)(j0 + r) * K_ + k0_ + s * 8;
            gload16(A0_ + ga, &As0[bi][0][0] + (size_t)idx * 8);
            gload16(A1_ + ga, &As1[bi][0][0] + (size_t)idx * 8);
            gload16(B0_ + gb, &Bs0[bi][0][0] + (size_t)idx * 8);
            gload16(B1_ + gb, &Bs1[bi][0][0] + (size_t)idx * 8);
        }
    };

    f32x4 acc[4][4] = {};
    stage(0, 0);
    __syncthreads();
    for (int ks = 0; ks < 48; ++ks) {
        const int cur = ks & 1;
        if (ks + 1 < 48) stage(ks + 1, cur ^ 1);   // prefetch next tile (other buffer)
        bf16x8 a0[4], a1[4];
#pragma unroll
        for (int mi = 0; mi < 4; ++mi) {
            int r = wrow * 64 + mi * 16 + cc;
            a0[mi] = *(const bf16x8*)&As0[cur][r][g * 8];
            a1[mi] = *(const bf16x8*)&As1[cur][r][g * 8];
        }
#pragma unroll
        for (int ni = 0; ni < 4; ++ni) {
            int n = wcol * 64 + ni * 16 + cc;
            bf16x8 bb0 = *(const bf16x8*)&Bs0[cur][n][g * 8];
            bf16x8 bb1 = *(const bf16x8*)&Bs1[cur][n][g * 8];
#pragma unroll
            for (int mi = 0; mi < 4; ++mi) {
                acc[mi][ni] = __builtin_amdgcn_mfma_f32_16x16x32_bf16(a0[mi], bb0, acc[mi][ni], 0, 0, 0);
                acc[mi][ni] = __builtin_amdgcn_mfma_f32_16x16x32_bf16(a0[mi], bb1, acc[mi][ni], 0, 0, 0);
                acc[mi][ni] = __builtin_amdgcn_mfma_f32_16x16x32_bf16(a1[mi], bb0, acc[mi][ni], 0, 0, 0);
            }
        }
        __syncthreads();   // drains vmcnt(0)+lgkm(0): prefetch landed, reads done
    }
    // epilogue (identical math to proven round-3 kernel)
#pragma unroll
    for (int ni = 0; ni < 4; ++ni) {
        int j = j0 + wcol * 64 + ni * 16 + cc;
        float cj = cvec[j];
#pragma unroll
        for (int mi = 0; mi < 4; ++mi) {
#pragma unroll
            for (int i = 0; i < 4; ++i) {
                int b = b0 + wrow * 64 + mi * 16 + g * 4 + i;
                float z = acc[mi][ni][i] + cj;
                float m = 1.0f / (1.0f + __expf(-z));
                float nv = noise[(size_t)b * NHID + j];
                hout[(size_t)b * NHID + j] = (nv < m) ? (unsigned short)0x3F80 : (unsigned short)0;
                if (fabsf(nv - m) < 2.5e-4f) {
                    unsigned p = atomicAdd(hcnt, 1u);
                    if (p < HCAP) hflag[p] = ((unsigned)b << 12) | (unsigned)j;
                }
            }
        }
    }
}

// ===========================================================================
// k2_p: pre = h@W^T + u@A + b ; per-(row,64col-block) top2.
// 128(M)x64(N) tile, 256 thr (4 waves, per-wave 64x32), double-buffered,
// 2-phase prefetch with __syncthreads. 48 KB LDS -> 3 blocks/CU.
// Unified 144-step loop: steps 0..127 = h@W^T (K=4096), 128..143 = u@A (K=512).
// grid (NVIS/64, BATCH/128) = (16,32)
// ===========================================================================
__global__ __launch_bounds__(256, 3) void k2_p(
    const unsigned short* __restrict__ hbf,
    const unsigned short* __restrict__ U0, const unsigned short* __restrict__ U1,
    const unsigned short* __restrict__ WR0, const unsigned short* __restrict__ WR1,
    const unsigned short* __restrict__ AT0, const unsigned short* __restrict__ AT1,
    const float* __restrict__ bvec, float4* __restrict__ blockbest)
{
    __shared__ __align__(16) unsigned short As0[2][128][32], As1[2][128][32],
                                            Bs0[2][64][32],  Bs1[2][64][32];
    __shared__ float4 mbuf[2][128];
    const int t = threadIdx.x, lane = t & 63, wid = t >> 6;
    const int g = lane >> 4, cc = lane & 15;
    const int wrow = wid >> 1, wcol = wid & 1;
    const int nwg = gridDim.x * gridDim.y;
    const int bid = blockIdx.y * gridDim.x + blockIdx.x;
    const int q = nwg >> 3;
    const int swz = (bid & 7) * q + (bid >> 3);
    const int b0 = (swz / gridDim.x) * 128;
    const int i0 = (swz % gridDim.x) * 64;

    // unified stage: all 256 threads stage every plane (r covers ALL rows)
    auto stageK = [&](int ks, int bi) {
        if (ks < 128) {                       // phase 1: A = h (1 plane), B = W rows (2 planes)
            const int k0 = ks * 32;
#pragma unroll
            for (int e = 0; e < 2; ++e) {
                int idx = t + e * 256, r = idx >> 2, s = idx & 3;
                gload16(hbf + (size_t)(b0 + r) * NHID + k0 + s * 8,
                        &As0[bi][0][0] + (size_t)idx * 8);
            }
            {
                int r = t >> 2, s = t & 3;    // r in 0..63: all 64 B-rows
                size_t go = (size_t)(i0 + r) * NHID + k0 + s * 8;
                gload16(WR0 + go, &Bs0[bi][0][0] + (size_t)t * 8);
                gload16(WR1 + go, &Bs1[bi][0][0] + (size_t)t * 8);
            }
        } else {                              // phase 2: A = u planes, B = A^T planes
            const int k0 = (ks - 128) * 32;
#pragma unroll
            for (int e = 0; e < 2; ++e) {
                int idx = t + e * 256, r = idx >> 2, s = idx & 3;
                size_t ga = (size_t)(b0 + r) * NCOND + k0 + s * 8;
                gload16(U0 + ga, &As0[bi][0][0] + (size_t)idx * 8);
                gload16(U1 + ga, &As1[bi][0][0] + (size_t)idx * 8);
            }
            {
                int r = t >> 2, s = t & 3;
                size_t go = (size_t)(i0 + r) * NCOND + k0 + s * 8;
                gload16(AT0 + go, &Bs0[bi][0][0] + (size_t)t * 8);
                gload16(AT1 + go, &Bs1[bi][0][0] + (size_t)t * 8);
            }
        }
    };

    f32x4 acc[4][2] = {};
    stageK(0, 0);
    __syncthreads();
    for (int ks = 0; ks < 144; ++ks) {
        const int cur = ks & 1;
        if (ks + 1 < 144) stageK(ks + 1, cur ^ 1);
        if (ks < 128) {
            bf16x8 a[4];
#pragma unroll
            for (int mi = 0; mi < 4; ++mi)
                a[mi] = *(const bf16x8*)&As0[cur][wrow * 64 + mi * 16 + cc][g * 8];
#pragma unroll
            for (int ni = 0; ni < 2; ++ni) {
                int n = wcol * 32 + ni * 16 + cc;
                bf16x8 bb0 = *(const bf16x8*)&Bs0[cur][n][g * 8];
                bf16x8 bb1 = *(const bf16x8*)&Bs1[cur][n][g * 8];
#pragma unroll
                for (int mi = 0; mi < 4; ++mi) {
                    acc[mi][ni] = __builtin_amdgcn_mfma_f32_16x16x32_bf16(a[mi], bb0, acc[mi][ni], 0, 0, 0);
                    acc[mi][ni] = __builtin_amdgcn_mfma_f32_16x16x32_bf16(a[mi], bb1, acc[mi][ni], 0, 0, 0);
                }
            }
        } else {
            bf16x8 a0[4], a1[4];
#pragma unroll
            for (int mi = 0; mi < 4; ++mi) {
                int r = wrow * 64 + mi * 16 + cc;
                a0[mi] = *(const bf16x8*)&As0[cur][r][g * 8];
                a1[mi] = *(const bf16x8*)&As1[cur][r][g * 8];
            }
#pragma unroll
            for (int ni = 0; ni < 2; ++ni) {
                int n = wcol * 32 + ni * 16 + cc;
                bf16x8 bb0 = *(const bf16x8*)&Bs0[cur][n][g * 8];
                bf16x8 bb1 = *(const bf16x8*)&Bs1[cur][n][g * 8];
#pragma unroll
                for (int mi = 0; mi < 4; ++mi) {
                    acc[mi][ni] = __builtin_amdgcn_mfma_f32_16x16x32_bf16(a0[mi], bb0, acc[mi][ni], 0, 0, 0);
                    acc[mi][ni] = __builtin_amdgcn_mfma_f32_16x16x32_bf16(a0[mi], bb1, acc[mi][ni], 0, 0, 0);
                    acc[mi][ni] = __builtin_amdgcn_mfma_f32_16x16x32_bf16(a1[mi], bb0, acc[mi][ni], 0, 0, 0);
                }
            }
        }
        __syncthreads();
    }

    // ---- epilogue: + bias, per-row top2 across this block's 64 cols ----
#pragma unroll
    for (int ni = 0; ni < 2; ++ni) {
        int colb = i0 + wcol * 32 + ni * 16 + cc;
        float bb = bvec[colb];
#pragma unroll
        for (int mi = 0; mi < 4; ++mi)
#pragma unroll
            for (int i = 0; i < 4; ++i) acc[mi][ni][i] += bb;
    }
#pragma unroll
    for (int mi = 0; mi < 4; ++mi) {
#pragma unroll
        for (int i = 0; i < 4; ++i) {
            float best = acc[mi][0][i];
            unsigned bidx = (unsigned)(i0 + wcol * 32 + cc);
            float sec = -3.4e38f;
            merge3(best, bidx, sec, acc[mi][1][i],
                   (unsigned)(i0 + wcol * 32 + 16 + cc), -3.4e38f);
#pragma unroll
            for (int m = 1; m < 16; m <<= 1) {
                float ob = __shfl_xor(best, m);
                unsigned oi = __shfl_xor(bidx, m);
                float os = __shfl_xor(sec, m);
                merge3(best, bidx, sec, ob, oi, os);
            }
            if (cc == 0)
                mbuf[wcol][wrow * 64 + mi * 16 + g * 4 + i] =
                    make_float4(best, sec, __uint_as_float(bidx), 0.f);
        }
    }
    __syncthreads();
    if (t < 128) {
        float4 f0 = mbuf[0][t], f1 = mbuf[1][t];
        float best = f0.x, sec = f0.y;
        unsigned bidx = __float_as_uint(f0.z);
        merge3(best, bidx, sec, f1.x, __float_as_uint(f1.z), f1.y);
        blockbest[(size_t)(b0 + t) * 16 + (unsigned)(i0 >> 6)] =
            make_float4(best, sec, __uint_as_float(bidx), 0.f);
    }
}

// ---------------- k5: exact f64 recheck of flagged h bits (bf16 h) ----------
__global__ __launch_bounds__(256) void k5_recheck_h(
    const float* __restrict__ vd, const float* __restrict__ cd, const float* __restrict__ noise,
    const float* __restrict__ W, const float* __restrict__ Bm, const float* __restrict__ cvec,
    const unsigned* __restrict__ hcnt, const unsigned* __restrict__ hflag,
    unsigned short* __restrict__ h) {
    const int gw = (blockIdx.x * 256 + threadIdx.x) >> 6, lane = threadIdx.x & 63;
    const int nw = gridDim.x * 4;
    unsigned n = *hcnt; if (n > HCAP) n = HCAP;
    for (unsigned e = gw; e < n; e += nw) {
        unsigned p = hflag[e];
        int b = p >> 12, j = p & 4095;
        double s = 0.0;
        for (int k = lane; k < NVIS; k += 64)
            s += (double)vd[(size_t)b * NVIS + k] * (double)W[(size_t)k * NHID + j];
        for (int k = lane; k < NCOND; k += 64)
            s += (double)cd[(size_t)b * NCOND + k] * (double)Bm[(size_t)k * NHID + j];
        for (int m = 32; m; m >>= 1) s += __shfl_xor(s, m);
        if (lane == 0) {
            double z = s + (double)cvec[j];
            double mm = 1.0 / (1.0 + exp(-z));
            h[(size_t)b * NHID + j] =
                ((double)noise[(size_t)b * NHID + j] < mm) ? (unsigned short)0x3F80 : (unsigned short)0;
        }
    }
}

// ---------------- k3: merge 16 block-top2 per row; flag near-ties ----------
__global__ __launch_bounds__(256) void k3_merge16(
    const float4* __restrict__ blockbest, unsigned* __restrict__ rowbest,
    unsigned* __restrict__ rcnt, unsigned* __restrict__ rowflag) {
    const int t = threadIdx.x;
    const int row = blockIdx.x * 16 + (t >> 4), e = t & 15;
    float4 f = blockbest[(size_t)row * 16 + e];
    float best = f.x, sec = f.y;
    unsigned idx = __float_as_uint(f.z);
#pragma unroll
    for (int m = 1; m < 16; m <<= 1) {
        float ob = __shfl_xor(best, m);
        unsigned oi = __shfl_xor(idx, m);
        float os = __shfl_xor(sec, m);
        merge3(best, idx, sec, ob, oi, os);
    }
    if (e == 0) {
        rowbest[row] = idx;
        if (best - sec < 8e-3f) {
            unsigned p = atomicAdd(rcnt, 1u);
            if (p < 4096) rowflag[p] = (unsigned)row;
        }
    }
}

// ---------------- onehot write (all rows, fast-path argmax) ----------------
__global__ __launch_bounds__(256) void k_onehot(const unsigned* __restrict__ rowbest,
                                                float* __restrict__ out) {
    const int row = blockIdx.x;
    const unsigned idx = rowbest[row];
    const int base = threadIdx.x * 4;
    float4 o;
    o.x = (base + 0 == (int)idx) ? 1.f : 0.f;
    o.y = (base + 1 == (int)idx) ? 1.f : 0.f;
    o.z = (base + 2 == (int)idx) ? 1.f : 0.f;
    o.w = (base + 3 == (int)idx) ? 1.f : 0.f;
    *(float4*)(out + (size_t)row * NVIS + base) = o;
}

// ---------------- k6a: exact f64 pre for flagged rows ----------------------
__global__ __launch_bounds__(256) void k6_rows_pre(
    const unsigned short* __restrict__ h, const float* __restrict__ cd,
    const float* __restrict__ W, const float* __restrict__ A, const float* __restrict__ bvec,
    const unsigned* __restrict__ rcnt, const unsigned* __restrict__ rowflag,
    double* __restrict__ prebuf) {
    const int gw = (blockIdx.x * 256 + threadIdx.x) >> 6, lane = threadIdx.x & 63;
    const int nw = gridDim.x * 4;
    unsigned n = *rcnt; if (n > RCAP) n = RCAP;
    for (unsigned e = gw; e < n * 1024u; e += nw) {
        int ri = e >> 10, i = e & 1023;
        int b = (int)rowflag[ri];
        double s = 0.0;
        for (int k = lane; k < NHID; k += 64) {
            double hv = h[(size_t)b * NHID + k] ? 1.0 : 0.0;
            s += hv * (double)W[(size_t)i * NHID + k];
        }
        for (int k = lane; k < NCOND; k += 64)
            s += (double)cd[(size_t)b * NCOND + k] * (double)A[(size_t)k * NVIS + i];
        for (int m = 32; m; m >>= 1) s += __shfl_xor(s, m);
        if (lane == 0) prebuf[(size_t)ri * 1024 + i] = s + (double)bvec[i];
    }
}

// ---------------- k6b: exact argmax + rewrite flagged rows -----------------
__global__ __launch_bounds__(256) void k6_rows_argmax(
    const unsigned* __restrict__ rcnt, const unsigned* __restrict__ rowflag,
    const double* __restrict__ prebuf, float* __restrict__ out) {
    __shared__ double sv[256];
    __shared__ int si[256];
    unsigned n = *rcnt; if (n > RCAP) n = RCAP;
    const int t = threadIdx.x;
    for (unsigned ri = blockIdx.x; ri < n; ri += gridDim.x) {
        const int row = (int)rowflag[ri];
        const double* pr = prebuf + (size_t)ri * 1024;
        double best = pr[t * 4];
        int bi = t * 4;
#pragma unroll
        for (int e = 1; e < 4; ++e) {
            double v = pr[t * 4 + e];
            if (v > best) { best = v; bi = t * 4 + e; }
        }
        sv[t] = best; si[t] = bi;
        __syncthreads();
        for (int s = 128; s; s >>= 1) {
            if (t < s) {
                double v2 = sv[t + s]; int i2 = si[t + s];
                if (v2 > sv[t] || (v2 == sv[t] && i2 < si[t])) { sv[t] = v2; si[t] = i2; }
            }
            __syncthreads();
        }
        const int amax = si[0];
        const int base = t * 4;
        float4 o;
        o.x = (base + 0 == amax) ? 1.f : 0.f;
        o.y = (base + 1 == amax) ? 1.f : 0.f;
        o.z = (base + 2 == amax) ? 1.f : 0.f;
        o.w = (base + 3 == amax) ? 1.f : 0.f;
        *(float4*)(out + (size_t)row * NVIS + base) = o;
        __syncthreads();
    }
}

// ---------------- launch ----------------
extern "C" void kernel_launch(void* const* d_in, const int* in_sizes, int n_in,
                              void* d_out, int out_size, void* d_ws, size_t ws_size,
                              hipStream_t stream) {
    const float* vd = (const float*)d_in[0];  // [4096,1024]
    const float* cd = (const float*)d_in[1];  // [4096,512]
    const float* nz = (const float*)d_in[2];  // [4096,4096]
    const float* W  = (const float*)d_in[3];  // [1024,4096]
    const float* bv = (const float*)d_in[4];  // [1024]
    const float* cv = (const float*)d_in[5];  // [4096]
    const float* Am = (const float*)d_in[6];  // [512,1024]
    const float* Bm = (const float*)d_in[7];  // [512,4096]
    float* out = (float*)d_out;
    char* w = (char*)d_ws;

    unsigned short* WT0  = (unsigned short*)(w + F_WT0);
    unsigned short* WT1  = (unsigned short*)(w + F_WT1);
    unsigned short* BmT0 = (unsigned short*)(w + F_BMT0);
    unsigned short* BmT1 = (unsigned short*)(w + F_BMT1);
    unsigned short* AT0  = (unsigned short*)(w + F_AT0);
    unsigned short* AT1  = (unsigned short*)(w + F_AT1);
    unsigned short* V0   = (unsigned short*)(w + F_V0);
    unsigned short* V1   = (unsigned short*)(w + F_V1);
    unsigned short* U0   = (unsigned short*)(w + F_U0);
    unsigned short* U1   = (unsigned short*)(w + F_U1);
    unsigned short* WR0  = (unsigned short*)(w + F_WR0);
    unsigned short* WR1  = (unsigned short*)(w + F_WR1);
    unsigned short* hbf  = (unsigned short*)(w + F_H);
    float4*   blockbest  = (float4*)(w + F_BB);
    unsigned* hflag      = (unsigned*)(w + F_HFLAG);
    unsigned* rowflag    = (unsigned*)(w + F_RFLAG);
    unsigned* rowbest    = (unsigned*)(w + F_RBEST);
    unsigned* counters   = (unsigned*)(w + F_CNT);
    double*   prebuf     = (double*)(w + F_PREB);
    unsigned* hcnt = &counters[0];
    unsigned* rcnt = &counters[1];

    dim3 blk(256);
    kz_zero<<<1, 64, 0, stream>>>(counters);
    transpose_split<<<dim3(NHID / 32, NVIS / 32), blk, 0, stream>>>(W, NVIS, NHID, WT0, WT1);
    transpose_split<<<dim3(NHID / 32, NCOND / 32), blk, 0, stream>>>(Bm, NCOND, NHID, BmT0, BmT1);
    transpose_split<<<dim3(NVIS / 32, NCOND / 32), blk, 0, stream>>>(Am, NCOND, NVIS, AT0, AT1);
    split_planes<<<2048, blk, 0, stream>>>(vd, BATCH * NVIS / 4, V0, V1);
    split_planes<<<2048, blk, 0, stream>>>(cd, BATCH * NCOND / 4, U0, U1);
    split_planes<<<2048, blk, 0, stream>>>(W, NVIS * NHID / 4, WR0, WR1);
    k1_p<<<dim3(NHID / 128, BATCH / 128), blk, 0, stream>>>(
        nz, V0, V1, U0, U1, WT0, WT1, BmT0, BmT1, cv, hbf, hcnt, hflag);
    k5_recheck_h<<<256, blk, 0, stream>>>(vd, cd, nz, W, Bm, cv, hcnt, hflag, hbf);
    k2_p<<<dim3(NVIS / 64, BATCH / 128), blk, 0, stream>>>(
        hbf, U0, U1, WR0, WR1, AT0, AT1, bv, blockbest);
    k3_merge16<<<BATCH / 16, blk, 0, stream>>>(blockbest, rowbest, rcnt, rowflag);
    k_onehot<<<BATCH, blk, 0, stream>>>(rowbest, out);
    k6_rows_pre<<<512, blk, 0, stream>>>(hbf, cd, W, Am, bv, rcnt, rowflag, prebuf);
    k6_rows_argmax<<<64, blk, 0, stream>>>(rcnt, rowflag, prebuf, out);
}

// Round 6
// 691.387 us; speedup vs baseline: 1.1823x; 1.1823x over previous
//
#include <hip/hip_runtime.h>
#include <math.h>

static constexpr int BATCH = 4096;
static constexpr int NVIS  = 1024;
static constexpr int NHID  = 4096;
static constexpr int NCOND = 512;

typedef __attribute__((ext_vector_type(8))) short bf16x8;
typedef __attribute__((ext_vector_type(4))) float f32x4;

static constexpr unsigned HCAP = 131072;
static constexpr unsigned RCAP = 256;
static constexpr size_t MB = 1u << 20;

// ---------------- ws layout (~101.6 MiB, proven) ----------------
static constexpr size_t F_WT0   = 0;                 // W^T planes [4096][1024]
static constexpr size_t F_WT1   = F_WT0  + 8*MB;
static constexpr size_t F_BMT0  = F_WT1  + 8*MB;     // B^T planes [4096][512]
static constexpr size_t F_BMT1  = F_BMT0 + 4*MB;
static constexpr size_t F_AT0   = F_BMT1 + 4*MB;     // A^T planes [1024][512]
static constexpr size_t F_AT1   = F_AT0  + 1*MB;
static constexpr size_t F_V0    = F_AT1  + 1*MB;     // vd planes [4096][1024]
static constexpr size_t F_V1    = F_V0   + 8*MB;
static constexpr size_t F_U0    = F_V1   + 8*MB;     // cd planes [4096][512]
static constexpr size_t F_U1    = F_U0   + 4*MB;
static constexpr size_t F_WR0   = F_U1   + 4*MB;     // W row-major planes [1024][4096]
static constexpr size_t F_WR1   = F_WR0  + 8*MB;
static constexpr size_t F_H     = F_WR1  + 8*MB;     // h bf16 [4096][4096]
static constexpr size_t F_BB    = F_H    + 32*MB;    // blockbest [4096][16] float4
static constexpr size_t F_HFLAG = F_BB   + 1*MB;
static constexpr size_t F_RFLAG = F_HFLAG + 512*1024;
static constexpr size_t F_RBEST = F_RFLAG + 16384;
static constexpr size_t F_CNT   = F_RBEST + 16384;
static constexpr size_t F_PREB  = F_CNT  + 256;
static constexpr size_t WS_FULL = F_PREB + 2*MB;

// ---------------- helpers ----------------
__device__ __forceinline__ void gload16(const void* g, void* l) {
    __builtin_amdgcn_global_load_lds(
        (const __attribute__((address_space(1))) void*)g,
        (__attribute__((address_space(3))) void*)l, 16, 0, 0);
}

__device__ __forceinline__ void split1(float x, unsigned short& hi, unsigned short& lo) {
    unsigned u = __float_as_uint(x);
    unsigned r = u + 0x7FFFu + ((u >> 16) & 1u);      // RN-even f32->bf16
    hi = (unsigned short)(r >> 16);
    float rem = x - __uint_as_float(r & 0xFFFF0000u); // exact (Sterbenz)
    unsigned u2 = __float_as_uint(rem);
    unsigned r2 = u2 + 0x7FFFu + ((u2 >> 16) & 1u);
    lo = (unsigned short)(r2 >> 16);
}

// top2 merge with first-index tiebreak; invariant s<=b on both inputs
__device__ __forceinline__ void merge3(float& b, unsigned& ix, float& s,
                                       float b2, unsigned i2, float s2) {
    if (b2 > b || (b2 == b && i2 < ix)) { s = fmaxf(b, s2); b = b2; ix = i2; }
    else                                { s = fmaxf(s, b2); }
}

// ---------------- prep kernels ----------------
__global__ void kz_zero(unsigned* c) { if (threadIdx.x < 64) c[threadIdx.x] = 0; }

// src [R][C] f32 -> d0/d1 [C][R] bf16 hi/lo planes
__global__ __launch_bounds__(256) void transpose_split(
    const float* __restrict__ src, int R, int C,
    unsigned short* __restrict__ d0, unsigned short* __restrict__ d1) {
    __shared__ float tile[32][33];
    const int c0 = blockIdx.x * 32, r0 = blockIdx.y * 32;
    const int tx = threadIdx.x & 31, ty = threadIdx.x >> 5;
#pragma unroll
    for (int e = 0; e < 4; ++e)
        tile[ty + e * 8][tx] = src[(size_t)(r0 + ty + e * 8) * C + c0 + tx];
    __syncthreads();
#pragma unroll
    for (int e = 0; e < 4; ++e) {
        int c = c0 + ty + e * 8;
        unsigned short hi, lo;
        split1(tile[tx][ty + e * 8], hi, lo);
        d0[(size_t)c * R + r0 + tx] = hi;
        d1[(size_t)c * R + r0 + tx] = lo;
    }
}

// elementwise split: src f32[n4*4] -> p0/p1 bf16 planes (same layout)
__global__ __launch_bounds__(256) void split_planes(
    const float* __restrict__ src, int n4,
    unsigned short* __restrict__ p0, unsigned short* __restrict__ p1) {
    for (int i = blockIdx.x * 256 + threadIdx.x; i < n4; i += gridDim.x * 256) {
        float4 v = ((const float4*)src)[i];
        unsigned short h0,h1,h2,h3,l0,l1,l2,l3;
        split1(v.x,h0,l0); split1(v.y,h1,l1); split1(v.z,h2,l2); split1(v.w,h3,l3);
        ((ushort4*)p0)[i] = make_ushort4(h0,h1,h2,h3);
        ((ushort4*)p1)[i] = make_ushort4(l0,l1,l2,l3);
    }
}

// ===========================================================================
// k1_p: z = v@W + u@B + c ; h(bf16) = noise < sigmoid(z); flag boundary bits.
// 128x128 tile, dbuf prefetch + __syncthreads. LDS chunk-XOR swizzle:
// physical chunk (r,s) holds global chunk s^((r>>1)&3); reads at g^((cc>>1)&3).
// Bank math: base = 16(cc&1)+4(g^((cc>>1)&3)) -> 8 quads x 2 lanes = free.
// grid (NHID/128, BATCH/128) = (32,32)
// ===========================================================================
__global__ __launch_bounds__(256, 2) void k1_p(
    const float* __restrict__ noise,
    const unsigned short* __restrict__ V0, const unsigned short* __restrict__ V1,
    const unsigned short* __restrict__ U0, const unsigned short* __restrict__ U1,
    const unsigned short* __restrict__ WT0, const unsigned short* __restrict__ WT1,
    const unsigned short* __restrict__ BmT0, const unsigned short* __restrict__ BmT1,
    const float* __restrict__ cvec, unsigned short* __restrict__ hout,
    unsigned* __restrict__ hcnt, unsigned* __restrict__ hflag)
{
    __shared__ __align__(16) unsigned short As0[2][128][32], As1[2][128][32],
                                            Bs0[2][128][32], Bs1[2][128][32];
    const int t = threadIdx.x, lane = t & 63, wid = t >> 6;
    const int g = lane >> 4, cc = lane & 15;
    const int wrow = wid >> 1, wcol = wid & 1;
    const int pc = (g ^ ((cc >> 1) & 3)) * 8;     // swizzled read chunk (ushorts)
    // XCD-aware bijective swizzle (nwg = 1024, divisible by 8)
    const int nwg = gridDim.x * gridDim.y;
    const int bid = blockIdx.y * gridDim.x + blockIdx.x;
    const int q = nwg >> 3;
    const int swz = (bid & 7) * q + (bid >> 3);
    const int b0 = (swz / gridDim.x) * 128;
    const int j0 = (swz % gridDim.x) * 128;

    auto stage = [&](int ks, int bi) {
        const unsigned short *A0_, *A1_, *B0_, *B1_; int K_, k0_;
        if (ks < 32) { A0_ = V0; A1_ = V1; B0_ = WT0; B1_ = WT1; K_ = 1024; k0_ = ks * 32; }
        else         { A0_ = U0; A1_ = U1; B0_ = BmT0; B1_ = BmT1; K_ = 512; k0_ = (ks - 32) * 32; }
#pragma unroll
        for (int e = 0; e < 2; ++e) {
            int idx = t + e * 256, r = idx >> 2, s = idx & 3;
            int sc = s ^ ((r >> 1) & 3);           // pre-swizzled global source chunk
            size_t ga = (size_t)(b0 + r) * K_ + k0_ + sc * 8;
            size_t gb = (size_t)(j0 + r) * K_ + k0_ + sc * 8;
            gload16(A0_ + ga, &As0[bi][0][0] + (size_t)idx * 8);
            gload16(A1_ + ga, &As1[bi][0][0] + (size_t)idx * 8);
            gload16(B0_ + gb, &Bs0[bi][0][0] + (size_t)idx * 8);
            gload16(B1_ + gb, &Bs1[bi][0][0] + (size_t)idx * 8);
        }
    };

    f32x4 acc[4][4] = {};
    stage(0, 0);
    __syncthreads();
    for (int ks = 0; ks < 48; ++ks) {
        const int cur = ks & 1;
        if (ks + 1 < 48) stage(ks + 1, cur ^ 1);   // prefetch next tile (other buffer)
        bf16x8 a0[4], a1[4];
#pragma unroll
        for (int mi = 0; mi < 4; ++mi) {
            int r = wrow * 64 + mi * 16 + cc;
            a0[mi] = *(const bf16x8*)&As0[cur][r][pc];
            a1[mi] = *(const bf16x8*)&As1[cur][r][pc];
        }
#pragma unroll
        for (int ni = 0; ni < 4; ++ni) {
            int n = wcol * 64 + ni * 16 + cc;
            bf16x8 bb0 = *(const bf16x8*)&Bs0[cur][n][pc];
            bf16x8 bb1 = *(const bf16x8*)&Bs1[cur][n][pc];
#pragma unroll
            for (int mi = 0; mi < 4; ++mi) {
                acc[mi][ni] = __builtin_amdgcn_mfma_f32_16x16x32_bf16(a0[mi], bb0, acc[mi][ni], 0, 0, 0);
                acc[mi][ni] = __builtin_amdgcn_mfma_f32_16x16x32_bf16(a0[mi], bb1, acc[mi][ni], 0, 0, 0);
                acc[mi][ni] = __builtin_amdgcn_mfma_f32_16x16x32_bf16(a1[mi], bb0, acc[mi][ni], 0, 0, 0);
            }
        }
        __syncthreads();   // drains vmcnt+lgkm: prefetch landed, reads done
    }
    // epilogue (identical math to proven kernels)
#pragma unroll
    for (int ni = 0; ni < 4; ++ni) {
        int j = j0 + wcol * 64 + ni * 16 + cc;
        float cj = cvec[j];
#pragma unroll
        for (int mi = 0; mi < 4; ++mi) {
#pragma unroll
            for (int i = 0; i < 4; ++i) {
                int b = b0 + wrow * 64 + mi * 16 + g * 4 + i;
                float z = acc[mi][ni][i] + cj;
                float m = 1.0f / (1.0f + __expf(-z));
                float nv = noise[(size_t)b * NHID + j];
                hout[(size_t)b * NHID + j] = (nv < m) ? (unsigned short)0x3F80 : (unsigned short)0;
                if (fabsf(nv - m) < 2.5e-4f) {
                    unsigned p = atomicAdd(hcnt, 1u);
                    if (p < HCAP) hflag[p] = ((unsigned)b << 12) | (unsigned)j;
                }
            }
        }
    }
}

// ===========================================================================
// k2_s: pre = h@W^T + u@A + b ; per-(row,64col-block) top2.
// 128(M)x64(N) tile, SERIAL stage->sync->compute (TLP-heavy: ~28KB LDS,
// high occupancy — round-5 evidence: TLP beats dbuf here). Same XOR swizzle.
// grid (NVIS/64, BATCH/128) = (16,32)
// ===========================================================================
__global__ __launch_bounds__(256, 4) void k2_s(
    const unsigned short* __restrict__ hbf,
    const unsigned short* __restrict__ U0, const unsigned short* __restrict__ U1,
    const unsigned short* __restrict__ WR0, const unsigned short* __restrict__ WR1,
    const unsigned short* __restrict__ AT0, const unsigned short* __restrict__ AT1,
    const float* __restrict__ bvec, float4* __restrict__ blockbest)
{
    __shared__ __align__(16) unsigned short As0[128][32], As1[128][32],
                                            Bs0[64][32],  Bs1[64][32];
    __shared__ float4 mbuf[2][128];
    const int t = threadIdx.x, lane = t & 63, wid = t >> 6;
    const int g = lane >> 4, cc = lane & 15;
    const int wrow = wid >> 1, wcol = wid & 1;
    const int pc = (g ^ ((cc >> 1) & 3)) * 8;
    const int nwg = gridDim.x * gridDim.y;
    const int bid = blockIdx.y * gridDim.x + blockIdx.x;
    const int q = nwg >> 3;
    const int swz = (bid & 7) * q + (bid >> 3);
    const int b0 = (swz / gridDim.x) * 128;
    const int i0 = (swz % gridDim.x) * 64;

    f32x4 acc[4][2] = {};

    // ---- phase 1: K = NHID; A = h (1 plane), B = W row-planes (2 planes) ----
    for (int k0 = 0; k0 < NHID; k0 += 32) {
        __syncthreads();
#pragma unroll
        for (int e = 0; e < 2; ++e) {
            int idx = t + e * 256, r = idx >> 2, s = idx & 3;
            int sc = s ^ ((r >> 1) & 3);
            gload16(hbf + (size_t)(b0 + r) * NHID + k0 + sc * 8,
                    &As0[0][0] + (size_t)idx * 8);
        }
        {
            int r = t >> 2, s = t & 3;           // r in 0..63: all 64 B-rows
            int sc = s ^ ((r >> 1) & 3);
            size_t go = (size_t)(i0 + r) * NHID + k0 + sc * 8;
            gload16(WR0 + go, &Bs0[0][0] + (size_t)t * 8);
            gload16(WR1 + go, &Bs1[0][0] + (size_t)t * 8);
        }
        __syncthreads();
        bf16x8 a[4];
#pragma unroll
        for (int mi = 0; mi < 4; ++mi)
            a[mi] = *(const bf16x8*)&As0[wrow * 64 + mi * 16 + cc][pc];
#pragma unroll
        for (int ni = 0; ni < 2; ++ni) {
            int n = wcol * 32 + ni * 16 + cc;
            bf16x8 bb0 = *(const bf16x8*)&Bs0[n][pc];
            bf16x8 bb1 = *(const bf16x8*)&Bs1[n][pc];
#pragma unroll
            for (int mi = 0; mi < 4; ++mi) {
                acc[mi][ni] = __builtin_amdgcn_mfma_f32_16x16x32_bf16(a[mi], bb0, acc[mi][ni], 0, 0, 0);
                acc[mi][ni] = __builtin_amdgcn_mfma_f32_16x16x32_bf16(a[mi], bb1, acc[mi][ni], 0, 0, 0);
            }
        }
    }
    // ---- phase 2: K = NCOND; A = u planes, B = A^T planes ----
    for (int k0 = 0; k0 < NCOND; k0 += 32) {
        __syncthreads();
#pragma unroll
        for (int e = 0; e < 2; ++e) {
            int idx = t + e * 256, r = idx >> 2, s = idx & 3;
            int sc = s ^ ((r >> 1) & 3);
            size_t ga = (size_t)(b0 + r) * NCOND + k0 + sc * 8;
            gload16(U0 + ga, &As0[0][0] + (size_t)idx * 8);
            gload16(U1 + ga, &As1[0][0] + (size_t)idx * 8);
        }
        {
            int r = t >> 2, s = t & 3;
            int sc = s ^ ((r >> 1) & 3);
            size_t go = (size_t)(i0 + r) * NCOND + k0 + sc * 8;
            gload16(AT0 + go, &Bs0[0][0] + (size_t)t * 8);
            gload16(AT1 + go, &Bs1[0][0] + (size_t)t * 8);
        }
        __syncthreads();
        bf16x8 a0[4], a1[4];
#pragma unroll
        for (int mi = 0; mi < 4; ++mi) {
            int r = wrow * 64 + mi * 16 + cc;
            a0[mi] = *(const bf16x8*)&As0[r][pc];
            a1[mi] = *(const bf16x8*)&As1[r][pc];
        }
#pragma unroll
        for (int ni = 0; ni < 2; ++ni) {
            int n = wcol * 32 + ni * 16 + cc;
            bf16x8 bb0 = *(const bf16x8*)&Bs0[n][pc];
            bf16x8 bb1 = *(const bf16x8*)&Bs1[n][pc];
#pragma unroll
            for (int mi = 0; mi < 4; ++mi) {
                acc[mi][ni] = __builtin_amdgcn_mfma_f32_16x16x32_bf16(a0[mi], bb0, acc[mi][ni], 0, 0, 0);
                acc[mi][ni] = __builtin_amdgcn_mfma_f32_16x16x32_bf16(a0[mi], bb1, acc[mi][ni], 0, 0, 0);
                acc[mi][ni] = __builtin_amdgcn_mfma_f32_16x16x32_bf16(a1[mi], bb0, acc[mi][ni], 0, 0, 0);
            }
        }
    }

    // ---- epilogue: + bias, per-row top2 across this block's 64 cols ----
#pragma unroll
    for (int ni = 0; ni < 2; ++ni) {
        int colb = i0 + wcol * 32 + ni * 16 + cc;
        float bb = bvec[colb];
#pragma unroll
        for (int mi = 0; mi < 4; ++mi)
#pragma unroll
            for (int i = 0; i < 4; ++i) acc[mi][ni][i] += bb;
    }
#pragma unroll
    for (int mi = 0; mi < 4; ++mi) {
#pragma unroll
        for (int i = 0; i < 4; ++i) {
            float best = acc[mi][0][i];
            unsigned bidx = (unsigned)(i0 + wcol * 32 + cc);
            float sec = -3.4e38f;
            merge3(best, bidx, sec, acc[mi][1][i],
                   (unsigned)(i0 + wcol * 32 + 16 + cc), -3.4e38f);
#pragma unroll
            for (int m = 1; m < 16; m <<= 1) {
                float ob = __shfl_xor(best, m);
                unsigned oi = __shfl_xor(bidx, m);
                float os = __shfl_xor(sec, m);
                merge3(best, bidx, sec, ob, oi, os);
            }
            if (cc == 0)
                mbuf[wcol][wrow * 64 + mi * 16 + g * 4 + i] =
                    make_float4(best, sec, __uint_as_float(bidx), 0.f);
        }
    }
    __syncthreads();
    if (t < 128) {
        float4 f0 = mbuf[0][t], f1 = mbuf[1][t];
        float best = f0.x, sec = f0.y;
        unsigned bidx = __float_as_uint(f0.z);
        merge3(best, bidx, sec, f1.x, __float_as_uint(f1.z), f1.y);
        blockbest[(size_t)(b0 + t) * 16 + (unsigned)(i0 >> 6)] =
            make_float4(best, sec, __uint_as_float(bidx), 0.f);
    }
}

// ---------------- k5: exact f64 recheck of flagged h bits (bf16 h) ----------
__global__ __launch_bounds__(256) void k5_recheck_h(
    const float* __restrict__ vd, const float* __restrict__ cd, const float* __restrict__ noise,
    const float* __restrict__ W, const float* __restrict__ Bm, const float* __restrict__ cvec,
    const unsigned* __restrict__ hcnt, const unsigned* __restrict__ hflag,
    unsigned short* __restrict__ h) {
    const int gw = (blockIdx.x * 256 + threadIdx.x) >> 6, lane = threadIdx.x & 63;
    const int nw = gridDim.x * 4;
    unsigned n = *hcnt; if (n > HCAP) n = HCAP;
    for (unsigned e = gw; e < n; e += nw) {
        unsigned p = hflag[e];
        int b = p >> 12, j = p & 4095;
        double s = 0.0;
        for (int k = lane; k < NVIS; k += 64)
            s += (double)vd[(size_t)b * NVIS + k] * (double)W[(size_t)k * NHID + j];
        for (int k = lane; k < NCOND; k += 64)
            s += (double)cd[(size_t)b * NCOND + k] * (double)Bm[(size_t)k * NHID + j];
        for (int m = 32; m; m >>= 1) s += __shfl_xor(s, m);
        if (lane == 0) {
            double z = s + (double)cvec[j];
            double mm = 1.0 / (1.0 + exp(-z));
            h[(size_t)b * NHID + j] =
                ((double)noise[(size_t)b * NHID + j] < mm) ? (unsigned short)0x3F80 : (unsigned short)0;
        }
    }
}

// ---------------- k3: merge 16 block-top2 per row; flag near-ties ----------
__global__ __launch_bounds__(256) void k3_merge16(
    const float4* __restrict__ blockbest, unsigned* __restrict__ rowbest,
    unsigned* __restrict__ rcnt, unsigned* __restrict__ rowflag) {
    const int t = threadIdx.x;
    const int row = blockIdx.x * 16 + (t >> 4), e = t & 15;
    float4 f = blockbest[(size_t)row * 16 + e];
    float best = f.x, sec = f.y;
    unsigned idx = __float_as_uint(f.z);
#pragma unroll
    for (int m = 1; m < 16; m <<= 1) {
        float ob = __shfl_xor(best, m);
        unsigned oi = __shfl_xor(idx, m);
        float os = __shfl_xor(sec, m);
        merge3(best, idx, sec, ob, oi, os);
    }
    if (e == 0) {
        rowbest[row] = idx;
        if (best - sec < 8e-3f) {
            unsigned p = atomicAdd(rcnt, 1u);
            if (p < 4096) rowflag[p] = (unsigned)row;
        }
    }
}

// ---------------- onehot write (all rows, fast-path argmax) ----------------
__global__ __launch_bounds__(256) void k_onehot(const unsigned* __restrict__ rowbest,
                                                float* __restrict__ out) {
    const int row = blockIdx.x;
    const unsigned idx = rowbest[row];
    const int base = threadIdx.x * 4;
    float4 o;
    o.x = (base + 0 == (int)idx) ? 1.f : 0.f;
    o.y = (base + 1 == (int)idx) ? 1.f : 0.f;
    o.z = (base + 2 == (int)idx) ? 1.f : 0.f;
    o.w = (base + 3 == (int)idx) ? 1.f : 0.f;
    *(float4*)(out + (size_t)row * NVIS + base) = o;
}

// ---------------- k6a: exact f64 pre for flagged rows ----------------------
__global__ __launch_bounds__(256) void k6_rows_pre(
    const unsigned short* __restrict__ h, const float* __restrict__ cd,
    const float* __restrict__ W, const float* __restrict__ A, const float* __restrict__ bvec,
    const unsigned* __restrict__ rcnt, const unsigned* __restrict__ rowflag,
    double* __restrict__ prebuf) {
    const int gw = (blockIdx.x * 256 + threadIdx.x) >> 6, lane = threadIdx.x & 63;
    const int nw = gridDim.x * 4;
    unsigned n = *rcnt; if (n > RCAP) n = RCAP;
    for (unsigned e = gw; e < n * 1024u; e += nw) {
        int ri = e >> 10, i = e & 1023;
        int b = (int)rowflag[ri];
        double s = 0.0;
        for (int k = lane; k < NHID; k += 64) {
            double hv = h[(size_t)b * NHID + k] ? 1.0 : 0.0;
            s += hv * (double)W[(size_t)i * NHID + k];
        }
        for (int k = lane; k < NCOND; k += 64)
            s += (double)cd[(size_t)b * NCOND + k] * (double)A[(size_t)k * NVIS + i];
        for (int m = 32; m; m >>= 1) s += __shfl_xor(s, m);
        if (lane == 0) prebuf[(size_t)ri * 1024 + i] = s + (double)bvec[i];
    }
}

// ---------------- k6b: exact argmax + rewrite flagged rows -----------------
__global__ __launch_bounds__(256) void k6_rows_argmax(
    const unsigned* __restrict__ rcnt, const unsigned* __restrict__ rowflag,
    const double* __restrict__ prebuf, float* __restrict__ out) {
    __shared__ double sv[256];
    __shared__ int si[256];
    unsigned n = *rcnt; if (n > RCAP) n = RCAP;
    const int t = threadIdx.x;
    for (unsigned ri = blockIdx.x; ri < n; ri += gridDim.x) {
        const int row = (int)rowflag[ri];
        const double* pr = prebuf + (size_t)ri * 1024;
        double best = pr[t * 4];
        int bi = t * 4;
#pragma unroll
        for (int e = 1; e < 4; ++e) {
            double v = pr[t * 4 + e];
            if (v > best) { best = v; bi = t * 4 + e; }
        }
        sv[t] = best; si[t] = bi;
        __syncthreads();
        for (int s = 128; s; s >>= 1) {
            if (t < s) {
                double v2 = sv[t + s]; int i2 = si[t + s];
                if (v2 > sv[t] || (v2 == sv[t] && i2 < si[t])) { sv[t] = v2; si[t] = i2; }
            }
            __syncthreads();
        }
        const int amax = si[0];
        const int base = t * 4;
        float4 o;
        o.x = (base + 0 == amax) ? 1.f : 0.f;
        o.y = (base + 1 == amax) ? 1.f : 0.f;
        o.z = (base + 2 == amax) ? 1.f : 0.f;
        o.w = (base + 3 == amax) ? 1.f : 0.f;
        *(float4*)(out + (size_t)row * NVIS + base) = o;
        __syncthreads();
    }
}

// ---------------- launch ----------------
extern "C" void kernel_launch(void* const* d_in, const int* in_sizes, int n_in,
                              void* d_out, int out_size, void* d_ws, size_t ws_size,
                              hipStream_t stream) {
    const float* vd = (const float*)d_in[0];  // [4096,1024]
    const float* cd = (const float*)d_in[1];  // [4096,512]
    const float* nz = (const float*)d_in[2];  // [4096,4096]
    const float* W  = (const float*)d_in[3];  // [1024,4096]
    const float* bv = (const float*)d_in[4];  // [1024]
    const float* cv = (const float*)d_in[5];  // [4096]
    const float* Am = (const float*)d_in[6];  // [512,1024]
    const float* Bm = (const float*)d_in[7];  // [512,4096]
    float* out = (float*)d_out;
    char* w = (char*)d_ws;

    unsigned short* WT0  = (unsigned short*)(w + F_WT0);
    unsigned short* WT1  = (unsigned short*)(w + F_WT1);
    unsigned short* BmT0 = (unsigned short*)(w + F_BMT0);
    unsigned short* BmT1 = (unsigned short*)(w + F_BMT1);
    unsigned short* AT0  = (unsigned short*)(w + F_AT0);
    unsigned short* AT1  = (unsigned short*)(w + F_AT1);
    unsigned short* V0   = (unsigned short*)(w + F_V0);
    unsigned short* V1   = (unsigned short*)(w + F_V1);
    unsigned short* U0   = (unsigned short*)(w + F_U0);
    unsigned short* U1   = (unsigned short*)(w + F_U1);
    unsigned short* WR0  = (unsigned short*)(w + F_WR0);
    unsigned short* WR1  = (unsigned short*)(w + F_WR1);
    unsigned short* hbf  = (unsigned short*)(w + F_H);
    float4*   blockbest  = (float4*)(w + F_BB);
    unsigned* hflag      = (unsigned*)(w + F_HFLAG);
    unsigned* rowflag    = (unsigned*)(w + F_RFLAG);
    unsigned* rowbest    = (unsigned*)(w + F_RBEST);
    unsigned* counters   = (unsigned*)(w + F_CNT);
    double*   prebuf     = (double*)(w + F_PREB);
    unsigned* hcnt = &counters[0];
    unsigned* rcnt = &counters[1];

    dim3 blk(256);
    kz_zero<<<1, 64, 0, stream>>>(counters);
    transpose_split<<<dim3(NHID / 32, NVIS / 32), blk, 0, stream>>>(W, NVIS, NHID, WT0, WT1);
    transpose_split<<<dim3(NHID / 32, NCOND / 32), blk, 0, stream>>>(Bm, NCOND, NHID, BmT0, BmT1);
    transpose_split<<<dim3(NVIS / 32, NCOND / 32), blk, 0, stream>>>(Am, NCOND, NVIS, AT0, AT1);
    split_planes<<<2048, blk, 0, stream>>>(vd, BATCH * NVIS / 4, V0, V1);
    split_planes<<<2048, blk, 0, stream>>>(cd, BATCH * NCOND / 4, U0, U1);
    split_planes<<<2048, blk, 0, stream>>>(W, NVIS * NHID / 4, WR0, WR1);
    k1_p<<<dim3(NHID / 128, BATCH / 128), blk, 0, stream>>>(
        nz, V0, V1, U0, U1, WT0, WT1, BmT0, BmT1, cv, hbf, hcnt, hflag);
    k5_recheck_h<<<256, blk, 0, stream>>>(vd, cd, nz, W, Bm, cv, hcnt, hflag, hbf);
    k2_s<<<dim3(NVIS / 64, BATCH / 128), blk, 0, stream>>>(
        hbf, U0, U1, WR0, WR1, AT0, AT1, bv, blockbest);
    k3_merge16<<<BATCH / 16, blk, 0, stream>>>(blockbest, rowbest, rcnt, rowflag);
    k_onehot<<<BATCH, blk, 0, stream>>>(rowbest, out);
    k6_rows_pre<<<512, blk, 0, stream>>>(hbf, cd, W, Am, bv, rcnt, rowflag, prebuf);
    k6_rows_argmax<<<64, blk, 0, stream>>>(rcnt, rowflag, prebuf, out);
}